// Round 9
// baseline (357.738 us; speedup 1.0000x reference)
//
#include <hip/hip_runtime.h>
#include <math.h>

#define B_     32
#define N_     20
#define D_     64
#define NODE_F 16
#define EDGE_F 8
#define E_PER  40
#define PROP   5
#define NC2    190
#define ITERS  20
#define INV_TEMP 10.0f
#define TN (2*B_*N_)
#define NG (2*B_)

struct PairTab { int s[NC2]; int d[NC2]; };
constexpr PairTab make_pairs() {
    PairTab t{};
    int idx = 0;
    for (int i = 0; i < N_; ++i)
        for (int j = i + 1; j < N_; ++j) { t.s[idx] = i; t.d[idx] = j; ++idx; }
    return t;
}
__device__ constexpr PairTab PAIRS = make_pairs();

__device__ __forceinline__ float rlane(float x, int k) {
    return __int_as_float(__builtin_amdgcn_readlane(__float_as_int(x), k));
}
template<int CTRL>
__device__ __forceinline__ float dppmov(float x) {
    return __int_as_float(__builtin_amdgcn_update_dpp(
        0, __float_as_int(x), CTRL, 0xf, 0xf, false));
}
__device__ __forceinline__ float rowsum16(float x) {
    x += dppmov<0x121>(x); x += dppmov<0x122>(x);
    x += dppmov<0x124>(x); x += dppmov<0x128>(x);
    return x;
}
__device__ __forceinline__ float rowmax16(float x) {
    x = fmaxf(x, dppmov<0x121>(x)); x = fmaxf(x, dppmov<0x122>(x));
    x = fmaxf(x, dppmov<0x124>(x)); x = fmaxf(x, dppmov<0x128>(x));
    return x;
}
__device__ __forceinline__ float nrcp(float x) {
    float r = __builtin_amdgcn_rcpf(x);
    r = r * fmaf(-x, r, 2.0f);
    return r;
}

// ================= per-graph: encode + 5x(msg,update); batched k-loops, staged weights =================
__global__ __launch_bounds__(1024, 4) void k_prop(
    const float* __restrict__ nf, const float* __restrict__ ef,
    const int* __restrict__ fidx, const int* __restrict__ tidx,
    const float* __restrict__ Wn, const float* __restrict__ bn,
    const float* __restrict__ We, const float* __restrict__ be,
    const float* __restrict__ Wm1, const float* __restrict__ bm1,
    const float* __restrict__ Wm2, const float* __restrict__ bm2,
    const float* __restrict__ Wu1, const float* __restrict__ bu1,
    const float* __restrict__ Wu2, const float* __restrict__ bu2,
    float* __restrict__ hout)
{
    __shared__ __align__(16) float wbuf[8192];   // 32 KB weight swap buffer
    __shared__ __align__(16) float sh[20][64];
    __shared__ __align__(16) float sE1[40][64];  // edge layer-1 constant (incl bm1)
    __shared__ __align__(16) float sFT[40][64];  // phase A/C partials: [0..19] part0, [20..39] part1
    __shared__ __align__(16) float sa[20][64];
    __shared__ short sF[40], sD[40];
    int g = blockIdx.x, t = threadIdx.x, w = t >> 6, l = t & 63;
    int part = w >> 3, wl = w & 7;

    if (t < 40) {
        sF[t] = (short)(fidx[g * 40 + t] - g * 20);
        sD[t] = (short)(tidx[g * 40 + t] - g * 20);
    }
    // encode nodes
    for (int n = w; n < 20; n += 16) {
        float a = bn[l];
#pragma unroll
        for (int k = 0; k < NODE_F; ++k) a += nf[(g * 20 + n) * NODE_F + k] * Wn[k * 64 + l];
        sh[n][l] = a; sa[n][l] = 0.f;
    }
    // stage Wm1[128:192] (16KB), compute E1 (3 edges per wave)
    {
        const float4* s4 = (const float4*)(Wm1 + 128 * 64);
        float4* d4 = (float4*)wbuf;
        if (t < 1024) d4[t] = s4[t];
    }
    __syncthreads();
    {
        int e0 = w, e1 = w + 16, e2 = w + 32;
        bool h2 = (w < 8);
        int e2c = h2 ? e2 : 0;
        float m0 = be[l], m1 = be[l], m2 = be[l];
#pragma unroll
        for (int k = 0; k < EDGE_F; ++k) {
            float wv = We[k * 64 + l];
            m0 += ef[(g * 40 + e0) * EDGE_F + k] * wv;
            m1 += ef[(g * 40 + e1) * EDGE_F + k] * wv;
            m2 += ef[(g * 40 + e2c) * EDGE_F + k] * wv;
        }
        float a0 = bm1[l], a1 = a0, a2 = a0;
#pragma unroll 4
        for (int k = 0; k < 64; ++k) {
            float wv = wbuf[k * 64 + l];
            a0 += rlane(m0, k) * wv;
            a1 += rlane(m1, k) * wv;
            a2 += rlane(m2, k) * wv;
        }
        sE1[e0][l] = a0; sE1[e1][l] = a1;
        if (h2) sE1[e2][l] = a2;
    }

    for (int step = 0; step < PROP; ++step) {
        // ======== phase A: F/T node partials (Wm1 rows 0..127 = 32KB) ========
        __syncthreads();
        {
            const float4* s4 = (const float4*)Wm1;
            float4* d4 = (float4*)wbuf;
            d4[t] = s4[t]; d4[t + 1024] = s4[t + 1024];
        }
        __syncthreads();
        {
            bool h2 = (wl < 4);
            float x0 = sh[wl][l], x1 = sh[wl + 8][l];
            float x2 = h2 ? sh[wl + 16][l] : 0.f;
            float a0 = 0.f, a1 = 0.f, a2 = 0.f;
#pragma unroll 4
            for (int k = 0; k < 64; ++k) {
                float wv = wbuf[(part * 64 + k) * 64 + l];
                a0 += rlane(x0, k) * wv;
                a1 += rlane(x1, k) * wv;
                a2 += rlane(x2, k) * wv;
            }
            sFT[part * 20 + wl][l] = a0;
            sFT[part * 20 + wl + 8][l] = a1;
            if (h2) sFT[part * 20 + wl + 16][l] = a2;
        }
        // ======== phase B: msg layer2 + aggregate (Wm2 16KB) ========
        __syncthreads();
        {
            const float4* s4 = (const float4*)Wm2;
            float4* d4 = (float4*)wbuf;
            if (t < 1024) d4[t] = s4[t];
        }
        __syncthreads();
        {
            bool h2 = (w < 8);
            int e0 = w, e1 = w + 16, e2c = h2 ? w + 32 : 0;
            int f0 = sF[e0], d0 = sD[e0];
            int f1 = sF[e1], d1 = sD[e1];
            int f2 = sF[e2c], d2 = sD[e2c];
            float p0 = fmaxf(sFT[f0][l] + sFT[20 + d0][l] + sE1[e0][l], 0.f);
            float p1 = fmaxf(sFT[f1][l] + sFT[20 + d1][l] + sE1[e1][l], 0.f);
            float p2 = fmaxf(sFT[f2][l] + sFT[20 + d2][l] + sE1[e2c][l], 0.f);
            float o0 = bm2[l], o1 = o0, o2 = o0;
#pragma unroll 4
            for (int k = 0; k < 64; ++k) {
                float wv = wbuf[k * 64 + l];
                o0 += rlane(p0, k) * wv;
                o1 += rlane(p1, k) * wv;
                o2 += rlane(p2, k) * wv;
            }
            atomicAdd(&sa[d0][l], o0);
            atomicAdd(&sa[d1][l], o1);
            if (h2) atomicAdd(&sa[d2][l], o2);
        }
        // ======== phase C: update layer1 F/T-split (Wu1 32KB) ========
        __syncthreads();
        {
            const float4* s4 = (const float4*)Wu1;
            float4* d4 = (float4*)wbuf;
            d4[t] = s4[t]; d4[t + 1024] = s4[t + 1024];
        }
        __syncthreads();
        {
            bool h2 = (wl < 4);
            float y0 = part ? sa[wl][l] : sh[wl][l];
            float y1 = part ? sa[wl + 8][l] : sh[wl + 8][l];
            float y2 = h2 ? (part ? sa[wl + 16][l] : sh[wl + 16][l]) : 0.f;
            float a0 = 0.f, a1 = 0.f, a2 = 0.f;
#pragma unroll 4
            for (int k = 0; k < 64; ++k) {
                float wv = wbuf[(part * 64 + k) * 64 + l];
                a0 += rlane(y0, k) * wv;
                a1 += rlane(y1, k) * wv;
                a2 += rlane(y2, k) * wv;
            }
            sFT[part * 20 + wl][l] = a0;
            sFT[part * 20 + wl + 8][l] = a1;
            if (h2) sFT[part * 20 + wl + 16][l] = a2;
        }
        // ======== phase D: update layer2 (Wu2 16KB), 2 nodes for w<4 ========
        __syncthreads();
        {
            const float4* s4 = (const float4*)Wu2;
            float4* d4 = (float4*)wbuf;
            if (t < 1024) d4[t] = s4[t];
        }
        __syncthreads();
        {
            bool h1 = (w < 4);
            int n0 = w, n1c = h1 ? w + 16 : 0;
            float z0 = fmaxf(sFT[n0][l] + sFT[20 + n0][l] + bu1[l], 0.f);
            float z1 = fmaxf(sFT[n1c][l] + sFT[20 + n1c][l] + bu1[l], 0.f);
            float o0 = bu2[l], o1 = o0;
#pragma unroll 4
            for (int k = 0; k < 64; ++k) {
                float wv = wbuf[k * 64 + l];
                o0 += rlane(z0, k) * wv;
                o1 += rlane(z1, k) * wv;
            }
            sh[n0][l] = o0; sa[n0][l] = 0.f;
            if (h1) { sh[n1c][l] = o1; sa[n1c][l] = 0.f; }
        }
    }
    __syncthreads();
    for (int n = w; n < 20; n += 16) hout[(g * 20 + n) * 64 + l] = sh[n][l];
}

// ================= heterogeneous 512-thr: blocks 0..31 sim+sink190 (no spill), 32..285 edge MLP =================
__global__ __launch_bounds__(512, 2) void k_fuse(
    const float* __restrict__ h,
    const float* __restrict__ qadj, const float* __restrict__ cadj,
    const float* __restrict__ Ws1, const float* __restrict__ bs1,
    const float* __restrict__ Ws2, const float* __restrict__ bs2,
    const float* __restrict__ Wl1, const float* __restrict__ bl1,
    const float* __restrict__ Wl2, const float* __restrict__ bl2,
    float* __restrict__ emb, float* __restrict__ eplan, float* __restrict__ dout)
{
    __shared__ short sQs[192], sQd[192];
    __shared__ float sP[N_][N_];
    __shared__ float sVbuf[192];
    __shared__ __align__(16) float region[12288];  // edge: wb1(8192)+wb2(4096) | sink: colpart[8][200]+sT(800)+sLa(400)
    int t = threadIdx.x, w = t >> 6, l = t & 63;

    if (t < 192) {
        int tt = t < NC2 ? t : NC2 - 1;
        sQs[t] = (short)PAIRS.s[tt]; sQd[t] = (short)PAIRS.d[tt];
    }
    __syncthreads();

    if (blockIdx.x < 32) {
        // ======================= sim + sink190 =======================
        int b = blockIdx.x;
        if (t == 0) dout[b] = 0.f;
        float* colpart = region;           // [8][200]
        float* sT = region + 1600;         // [2][20][20]
        float* sLa = region + 2400;        // [20][20]

        // T MLPs: 5 rows per wave
        {
            int lk = (l < 20) ? l : 0;
#pragma unroll
            for (int s = 0; s < 5; ++s) {
                int r = w + 8 * s;
                float hv = h[(b * 40 + r) * 64 + l];
                float a = bs1[lk];
#pragma unroll 4
                for (int ff = 0; ff < 64; ++ff) a += rlane(hv, ff) * Ws1[ff * 20 + lk];
                a = fmaxf(a, 0.f);
                float t2 = bs2[lk];
#pragma unroll
                for (int j = 0; j < 20; ++j) t2 += rlane(a, j) * Ws2[j * 20 + lk];
                if (l < 20) sT[(r >= 20) * 400 + (r % 20) * 20 + l] = t2;
            }
        }
        __syncthreads();
        if (t < 400) {
            int i = t / 20, j = t % 20;
            float c = 0.f;
#pragma unroll
            for (int k = 0; k < 20; ++k) c += fabsf(sT[i * 20 + k] - sT[400 + j * 20 + k]);
            sLa[i * 20 + j] = -c * INV_TEMP;
        }
        __syncthreads();

        // single-wave register 20x20 log sinkhorn
        if (w == 0) {
            int q = l & 31, r2 = l >> 5;
            bool qok = (q < 20);
            float A20[10], u10[10];
#pragma unroll
            for (int i = 0; i < 10; ++i) {
                int r = 2 * i + r2;
                A20[i] = qok ? sLa[r * 20 + q] : -1e30f;
            }
            float vq = 0.f;
            for (int it = 0; it < ITERS; ++it) {
#pragma unroll
                for (int i = 0; i < 10; ++i) {
                    float x = A20[i] - vq;
                    float m = x;
#pragma unroll
                    for (int off = 16; off; off >>= 1) m = fmaxf(m, __shfl_xor(m, off));
                    float s = __expf(x - m);
#pragma unroll
                    for (int off = 16; off; off >>= 1) s += __shfl_xor(s, off);
                    u10[i] = m + __logf(s);
                }
                float pm = -1e30f;
#pragma unroll
                for (int i = 0; i < 10; ++i) pm = fmaxf(pm, A20[i] - u10[i]);
                float ps = 0.f;
#pragma unroll
                for (int i = 0; i < 10; ++i) ps += __expf(A20[i] - u10[i] - pm);
                float om = __shfl_xor(pm, 32), os = __shfl_xor(ps, 32);
                float M = fmaxf(pm, om);
                float S = ps * __expf(pm - M) + os * __expf(om - M);
                vq = M + __logf(S);
                if (!qok) vq = 0.f;
            }
#pragma unroll
            for (int i = 0; i < 10; ++i) {
                int r = 2 * i + r2;
                if (qok) sP[r][q] = __expf(A20[i] - u10[i] - vq);
            }
        }
        __syncthreads();

        // ---- sink190: thread owns rows p=rslot+32i (i<6), cols q=l16+16j (j<12) ----
        int g4 = l >> 4, l16 = l & 15, rslot = w * 4 + g4;  // rslot in [0,32)
        int sp[6], dp[6]; bool pv[6];
#pragma unroll
        for (int i = 0; i < 6; ++i) {
            int p = rslot + 32 * i;
            pv[i] = (p < NC2);
            int pc = pv[i] ? p : 0;
            sp[i] = sQs[pc]; dp[i] = sQd[pc];
        }
        int sq[12], dq[12]; bool qv[12];
#pragma unroll
        for (int j = 0; j < 12; ++j) {
            int q = l16 + 16 * j;
            qv[j] = (q < NC2);
            int qc = qv[j] ? q : 0;
            sq[j] = sQs[qc]; dq[j] = sQd[qc];
        }

        float AE[6][12];
#pragma unroll
        for (int i = 0; i < 6; ++i)
#pragma unroll
            for (int j = 0; j < 12; ++j) {
                if (pv[i] && qv[j]) {
                    float st = sP[sp[i]][sq[j]] * sP[dp[i]][dq[j]];
                    float cr = sP[sp[i]][dq[j]] * sP[dp[i]][sq[j]];
                    AE[i][j] = __logf(fmaxf(st, cr) + 1e-6f) * INV_TEMP;
                } else AE[i][j] = -1e30f;
            }

        // iter 1 in log domain (prevents later multiplicative underflow)
        float u[6];
#pragma unroll
        for (int i = 0; i < 6; ++i) {
            float m = -1e30f;
#pragma unroll
            for (int j = 0; j < 12; ++j) m = fmaxf(m, AE[i][j]);
            m = rowmax16(m);
            float s = 0.f;
#pragma unroll
            for (int j = 0; j < 12; ++j) s += __expf(AE[i][j] - m);
            s = rowsum16(s);
            u[i] = m + __logf(s);
            if (!pv[i]) u[i] = 0.f;
        }
#pragma unroll
        for (int j = 0; j < 12; ++j) {
            float pm = -1e30f;
#pragma unroll
            for (int i = 0; i < 6; ++i) if (pv[i]) pm = fmaxf(pm, AE[i][j] - u[i]);
            pm = fmaxf(pm, __shfl_xor(pm, 16));
            pm = fmaxf(pm, __shfl_xor(pm, 32));
            if (g4 == 0) colpart[w * 200 + l16 + 16 * j] = pm;
        }
        __syncthreads();
        if (t < 192) {
            float M = -1e30f;
#pragma unroll
            for (int s = 0; s < 8; ++s) M = fmaxf(M, colpart[s * 200 + t]);
            sVbuf[t] = M;
        }
        __syncthreads();
        float Mj[12];
#pragma unroll
        for (int j = 0; j < 12; ++j) Mj[j] = sVbuf[l16 + 16 * j];
#pragma unroll
        for (int j = 0; j < 12; ++j) {
            float ps = 0.f;
#pragma unroll
            for (int i = 0; i < 6; ++i) if (pv[i]) ps += __expf(AE[i][j] - u[i] - Mj[j]);
            ps += __shfl_xor(ps, 16);
            ps += __shfl_xor(ps, 32);
            if (g4 == 0) colpart[w * 200 + l16 + 16 * j] = ps;
        }
        __syncthreads();
        if (t < 192) {
            float S = 0.f;
#pragma unroll
            for (int s = 0; s < 8; ++s) S += colpart[s * 200 + t];
            sVbuf[t] = sVbuf[t] + __logf(fmaxf(S, 1e-37f));
        }
        __syncthreads();
#pragma unroll
        for (int j = 0; j < 12; ++j) Mj[j] = sVbuf[l16 + 16 * j];
#pragma unroll
        for (int i = 0; i < 6; ++i)
#pragma unroll
            for (int j = 0; j < 12; ++j) {
                float e = __expf(AE[i][j] - u[i] - Mj[j]);
                AE[i][j] = (pv[i] && qv[j]) ? e : 0.f;
            }
        __syncthreads();

        // iters 2..20 multiplicative
        float invS[6];
        for (int it = 0; it < ITERS - 1; ++it) {
#pragma unroll
            for (int i = 0; i < 6; ++i) {
                float s01 = AE[i][0] + AE[i][1], s23 = AE[i][2] + AE[i][3];
                float s45 = AE[i][4] + AE[i][5], s67 = AE[i][6] + AE[i][7];
                float s89 = AE[i][8] + AE[i][9], sab = AE[i][10] + AE[i][11];
                float S = ((s01 + s23) + (s45 + s67)) + (s89 + sab);
                S = rowsum16(S);
                invS[i] = nrcp(fmaxf(S, 1e-30f));
            }
#pragma unroll
            for (int j = 0; j < 12; ++j) {
                float pc = AE[0][j] * invS[0];
                pc = fmaf(AE[1][j], invS[1], pc);
                pc = fmaf(AE[2][j], invS[2], pc);
                pc = fmaf(AE[3][j], invS[3], pc);
                pc = fmaf(AE[4][j], invS[4], pc);
                pc = fmaf(AE[5][j], invS[5], pc);
                pc += __shfl_xor(pc, 16);
                pc += __shfl_xor(pc, 32);
                if (g4 == 0) colpart[w * 200 + l16 + 16 * j] = pc;
            }
            __syncthreads();
            if (t < 192) {
                float c = 0.f;
#pragma unroll
                for (int s = 0; s < 8; ++s) c += colpart[s * 200 + t];
                sVbuf[t] = nrcp(fmaxf(c, 1e-30f));
            }
            __syncthreads();
            float ic[12];
#pragma unroll
            for (int j = 0; j < 12; ++j) ic[j] = sVbuf[l16 + 16 * j];
#pragma unroll
            for (int i = 0; i < 6; ++i)
#pragma unroll
                for (int j = 0; j < 12; ++j) {
                    float tmp = AE[i][j] * invS[i];
                    AE[i][j] = tmp * ic[j];
                }
        }

        float* ep = eplan + (size_t)b * NC2 * NC2;
#pragma unroll
        for (int i = 0; i < 6; ++i) {
            if (pv[i]) {
                int p = rslot + 32 * i;
                float* row = ep + (size_t)p * NC2;
#pragma unroll
                for (int j = 0; j < 12; ++j)
                    if (qv[j]) row[l16 + 16 * j] = AE[i][j];
            }
        }
    } else {
        // ======================= edge MLP role (48 slots/block) =======================
        int eb = blockIdx.x - 32;
        float* wb1 = region;            // Wl1 rows 0..127
        float* wb2 = region + 8192;     // Wl2
        {
            const float4* s1 = (const float4*)Wl1;
            float4* d1 = (float4*)wb1;
#pragma unroll
            for (int i = 0; i < 4; ++i) d1[t + 512 * i] = s1[t + 512 * i];
            const float4* s2 = (const float4*)Wl2;
            float4* d2 = (float4*)wb2;
#pragma unroll
            for (int i = 0; i < 2; ++i) d2[t + 512 * i] = s2[t + 512 * i];
        }
        float b1 = bl1[l];
        float w128 = Wl1[128 * 64 + l];
        float b2 = 2.f * bl2[l];
        __syncthreads();

        int base = eb * 48 + w * 6;
        float sv[6], dv[6], av[6]; bool val[6]; int gi[6], pp[6];
#pragma unroll
        for (int s = 0; s < 6; ++s) {
            int sid = base + s;
            val[s] = (sid < NG * NC2);
            int sc = val[s] ? sid : 0;
            gi[s] = sc / NC2;               // graph index 0..63 (= 2b+gg)
            pp[s] = sc - gi[s] * NC2;
            int bb = gi[s] >> 1, gg = gi[s] & 1;
            int spi = sQs[pp[s]], dpi = sQd[pp[s]];
            sv[s] = h[(bb * 40 + gg * 20 + spi) * 64 + l];
            dv[s] = h[(bb * 40 + gg * 20 + dpi) * 64 + l];
            const float* adj = gg ? cadj : qadj;
            av[s] = adj[bb * 400 + spi * 20 + dpi];
        }
        float aF[6], aB[6];
#pragma unroll
        for (int s = 0; s < 6; ++s) { float t0 = b1 + av[s] * w128; aF[s] = t0; aB[s] = t0; }
#pragma unroll 2
        for (int k = 0; k < 64; ++k) {
            float w0 = wb1[k * 64 + l];
            float w1 = wb1[(64 + k) * 64 + l];
#pragma unroll
            for (int s = 0; s < 6; ++s) {
                float a = rlane(sv[s], k), c = rlane(dv[s], k);
                aF[s] += a * w0 + c * w1;
                aB[s] += c * w0 + a * w1;
            }
        }
        float hs[6], out[6];
#pragma unroll
        for (int s = 0; s < 6; ++s) { hs[s] = fmaxf(aF[s], 0.f) + fmaxf(aB[s], 0.f); out[s] = b2; }
#pragma unroll 4
        for (int k = 0; k < 64; ++k) {
            float ww = wb2[k * 64 + l];
#pragma unroll
            for (int s = 0; s < 6; ++s) out[s] += rlane(hs[s], k) * ww;
        }
#pragma unroll
        for (int s = 0; s < 6; ++s)
            if (val[s]) emb[((size_t)gi[s] * NC2 + pp[s]) * 64 + l] = out[s];
    }
}

// ================= final weighted L1 contraction =================
__global__ __launch_bounds__(256) void k_dist(
    const float* __restrict__ emb, const float* __restrict__ eplan, float* __restrict__ dout)
{
    int b = blockIdx.x, c = blockIdx.y;
    int w = threadIdx.x >> 6, l = threadIdx.x & 63;
    const float* qe = emb + (size_t)(2 * b) * NC2 * D_;
    const float* ce = emb + (size_t)(2 * b + 1) * NC2 * D_;
    const float* W = eplan + (size_t)b * NC2 * NC2;
    float acc = 0.f;
    int pbase = c * 16 + w * 4;
    for (int i = 0; i < 4; ++i) {
        int p = pbase + i;
        if (p >= NC2) break;
        float qv = qe[(size_t)p * D_ + l];
        const float* wrow = W + (size_t)p * NC2;
        for (int q = 0; q < NC2; ++q)
            acc += wrow[q] * fabsf(qv - ce[(size_t)q * D_ + l]);
    }
#pragma unroll
    for (int off = 32; off; off >>= 1) acc += __shfl_xor(acc, off);
    if (l == 0) atomicAdd(&dout[b], acc);
}

// ================= launch =================
extern "C" void kernel_launch(void* const* d_in, const int* in_sizes, int n_in,
                              void* d_out, int out_size, void* d_ws, size_t ws_size,
                              hipStream_t stream)
{
    const float* nf   = (const float*)d_in[0];
    const float* ef   = (const float*)d_in[1];
    const float* qadj = (const float*)d_in[2];
    const float* cadj = (const float*)d_in[3];
    const int*   fidx = (const int*)d_in[4];
    const int*   tidx = (const int*)d_in[5];
    const float* Wn  = (const float*)d_in[6];  const float* bn  = (const float*)d_in[7];
    const float* We  = (const float*)d_in[8];  const float* be  = (const float*)d_in[9];
    const float* Wm1 = (const float*)d_in[10]; const float* bm1 = (const float*)d_in[11];
    const float* Wm2 = (const float*)d_in[12]; const float* bm2 = (const float*)d_in[13];
    const float* Wu1 = (const float*)d_in[14]; const float* bu1 = (const float*)d_in[15];
    const float* Wu2 = (const float*)d_in[16]; const float* bu2 = (const float*)d_in[17];
    const float* Ws1 = (const float*)d_in[18]; const float* bs1 = (const float*)d_in[19];
    const float* Ws2 = (const float*)d_in[20]; const float* bs2 = (const float*)d_in[21];
    const float* Wl1 = (const float*)d_in[22]; const float* bl1 = (const float*)d_in[23];
    const float* Wl2 = (const float*)d_in[24]; const float* bl2 = (const float*)d_in[25];

    float* ws    = (float*)d_ws;
    float* h     = ws;                               // TN*64
    float* emb   = h + (size_t)TN * 64;              // NG*NC2*64
    float* eplan = emb + (size_t)NG * NC2 * 64;      // B*NC2*NC2
    float* dout  = (float*)d_out;

    k_prop<<<NG, 1024, 0, stream>>>(nf, ef, fidx, tidx, Wn, bn, We, be,
                                    Wm1, bm1, Wm2, bm2, Wu1, bu1, Wu2, bu2, h);
    k_fuse<<<32 + 254, 512, 0, stream>>>(h, qadj, cadj, Ws1, bs1, Ws2, bs2,
                                         Wl1, bl1, Wl2, bl2, emb, eplan, dout);
    k_dist<<<dim3(B_, 12), 256, 0, stream>>>(emb, eplan, dout);
}